// Round 18
// baseline (149.651 us; speedup 1.0000x reference)
//
#include <hip/hip_runtime.h>

typedef unsigned short u16;
typedef unsigned int   u32;
typedef short bf16x8 __attribute__((ext_vector_type(8)));
typedef float f32x2  __attribute__((ext_vector_type(2)));
typedef float f32x4  __attribute__((ext_vector_type(4)));
typedef float f32x16 __attribute__((ext_vector_type(16)));
typedef u32   u32x4  __attribute__((ext_vector_type(4)));

#define QK_SCALE 0.18033688011112042f   // 0.125 * log2(e): fold softmax exp2 into q

__device__ __forceinline__ u16 f2bf(float f) {
  u32 u = __builtin_bit_cast(u32, f);
  u = (u + 0x7FFFu + ((u >> 16) & 1u)) >> 16;   // RNE
  return (u16)u;
}

__device__ __forceinline__ u32 cvtpk(float lo, float hi) {
  u32 r;
  asm("v_cvt_pk_bf16_f32 %0, %1, %2" : "=v"(r) : "v"(lo), "v"(hi));
  return r;
}

__device__ __forceinline__ void gload16(void* lds, const void* g) {
  __builtin_amdgcn_global_load_lds(
      (const __attribute__((address_space(1))) u32*)g,
      (__attribute__((address_space(3))) u32*)lds, 16, 0, 0);
}

__device__ __forceinline__ bf16x8 ld8(const void* p) {
  return *(const bf16x8*)p;
}

__device__ __forceinline__ f32x16 fz16() { f32x16 z = {}; return z; }

// ---------------- kernel 1: fp32 -> bf16 convert (x, in_proj_w, out_w) ----
__global__ __launch_bounds__(256) void cvt_kernel(
    const float* __restrict__ x, const float* __restrict__ w1,
    const float* __restrict__ w2,
    u16* __restrict__ xb, u16* __restrict__ wb, u16* __restrict__ ob) {
  int i = blockIdx.x * 256 + threadIdx.x;      // one float4 per thread
  const float* src; u16* dst; int off;
  if (i < 1048576)            { src = x;  dst = xb; off = i; }
  else if (i < 1048576+196608){ src = w1; dst = wb; off = i - 1048576; }
  else                        { src = w2; dst = ob; off = i - 1245184; }
  float4 v = ((const float4*)src)[off];
  ushort4 o;
  o.x = f2bf(v.x); o.y = f2bf(v.y); o.z = f2bf(v.z); o.w = f2bf(v.w);
  ((ushort4*)dst)[off] = o;
}

// ---------------- kernel 2/5: bf16 GEMM  C = A * B^T  (+bias) -------------
template<int MODE>
__global__ __launch_bounds__(256, 2) void gemm_bt(
    const u16* __restrict__ A, const u16* __restrict__ Bm,
    const float* __restrict__ bias,
    u16* __restrict__ q_out, u16* __restrict__ k_out, u16* __restrict__ v_out,
    float* __restrict__ f_out, int M, int N, int K) {
  __shared__ __attribute__((aligned(16))) u16 As[128 * 64];
  __shared__ __attribute__((aligned(16))) u16 Bs[128 * 64];
  const int tid = threadIdx.x, lane = tid & 63, w = tid >> 6;
  const int wm = w >> 1, wn = w & 1;
  const int lo = lane & 15, hi = lane >> 4;
  const int m0 = blockIdx.x * 128, n0 = blockIdx.y * 128;
  f32x4 acc[4][4] = {};
  const int srow = lane >> 3;                   // row within 8-row chunk
  const int skc  = (lane & 7) ^ srow;           // pre-swizzled source chunk
  const int nk = K >> 6;
  for (int kt = 0; kt < nk; ++kt) {
    __syncthreads();                            // WAR on LDS
    const int k0 = kt * 64;
#pragma unroll
    for (int c = 0; c < 4; ++c) {
      const int ch = w * 4 + c;                 // 0..15, wave-uniform
      const int row = ch * 8 + srow;
      gload16((char*)As + ch * 1024, A  + (size_t)(m0 + row) * K + k0 + skc * 8);
      gload16((char*)Bs + ch * 1024, Bm + (size_t)(n0 + row) * K + k0 + skc * 8);
    }
    __syncthreads();                            // vmcnt(0) drained by compiler
#pragma unroll
    for (int kk = 0; kk < 2; ++kk) {
      bf16x8 af[4], bfr[4];
#pragma unroll
      for (int mi = 0; mi < 4; ++mi) {
        const int row = wm * 64 + mi * 16 + lo;
        const int kc = kk * 4 + hi;
        af[mi] = ld8((const char*)As + row * 128 + ((kc ^ (row & 7)) << 4));
      }
#pragma unroll
      for (int ni = 0; ni < 4; ++ni) {
        const int row = wn * 64 + ni * 16 + lo;
        const int kc = kk * 4 + hi;
        bfr[ni] = ld8((const char*)Bs + row * 128 + ((kc ^ (row & 7)) << 4));
      }
#pragma unroll
      for (int mi = 0; mi < 4; ++mi)
#pragma unroll
        for (int ni = 0; ni < 4; ++ni)
          acc[mi][ni] = __builtin_amdgcn_mfma_f32_16x16x32_bf16(
              af[mi], bfr[ni], acc[mi][ni], 0, 0, 0);
    }
  }
  // epilogue
#pragma unroll
  for (int mi = 0; mi < 4; ++mi)
#pragma unroll
    for (int ni = 0; ni < 4; ++ni) {
      const int gn = n0 + wn * 64 + ni * 16 + lo;
      const float bv = bias[gn];
#pragma unroll
      for (int r = 0; r < 4; ++r) {
        const int gm = m0 + wm * 64 + mi * 16 + hi * 4 + r;
        float val = acc[mi][ni][r] + bv;
        if (MODE == 0) {
          const int s = gm >> 1, b = gm & 1;
          const int sec = gn >> 9, e = gn & 511;
          const int h = e >> 6, d = e & 63;
          const size_t o = (((size_t)(b * 8 + h) * 4096 + s) << 6) + d;
          if (sec == 0)      q_out[o] = f2bf(val * QK_SCALE);
          else if (sec == 1) k_out[o] = f2bf(val);
          else               v_out[o] = f2bf(val);
        } else {
          f_out[(size_t)gm * N + gn] = val;
        }
      }
    }
}

// ---------------- kernel 3: V [BH][S][64] -> V^T [BH][64][S] --------------
__global__ __launch_bounds__(256) void transpose_v(
    const u16* __restrict__ v, u16* __restrict__ vt) {
  __shared__ __attribute__((aligned(16))) u16 T[64 * 72];
  const int bh = blockIdx.y, s0 = blockIdx.x * 64;
  const int t = threadIdx.x;
#pragma unroll
  for (int i = 0; i < 2; ++i) {
    const int idx = t + i * 256;                // 0..511
    const int row = idx >> 3, c = idx & 7;
    uint4 d = *(const uint4*)(v + ((size_t)bh * 4096 + s0 + row) * 64 + c * 8);
    *(uint4*)(&T[row * 72 + c * 8]) = d;
  }
  __syncthreads();
#pragma unroll
  for (int i = 0; i < 2; ++i) {
    const int idx = t + i * 256;
    const int dcol = idx >> 3, sc = idx & 7;
    u16 tmp[8];
#pragma unroll
    for (int j = 0; j < 8; ++j) tmp[j] = T[(sc * 8 + j) * 72 + dcol];
    *(uint4*)(vt + ((size_t)bh * 64 + dcol) * 4096 + s0 + sc * 8) = *(const uint4*)tmp;
  }
}

// ---------------- kernel 4: flash attention, 3-wave/SIMD variant ----------
// Grid 1024 (R8-verified mapping): block = 4 waves, wq = w&1 (32 q-rows of
// a 64-row block), kvh = w>>1 (kv half). Each wave: ONE q-subtile, 32 kv
// tiles of 64 (KVBLK=64), R11's verified PV-defer pipeline (pa/vfr of tile
// t live in regs across the barrier; PV(t-1) is a pure-register 8-MFMA
// cluster at the top of iteration t). LDS diet: K double-buffered (32 KB),
// V SINGLE-buffered (16 KB) -> 48.3 KB/block -> 3 blocks/CU = 3 waves/SIMD
// (R11 was LDS-capped at 2). V hazards: vfr(t) read from V_lds at top;
// barrier-2a = all waves done with V(t); stage V(t+1)+K(t+1) after 2a;
// barrier-2b (end) drains staging. Per-q-row math/order identical to R11.
// Max-free softmax (R8-verified): p = exp2(st), shift 0, merge by l-sums.
__global__ __launch_bounds__(256, 3) void fa_kernel(
    const u16* __restrict__ q, const u16* __restrict__ k,
    const u16* __restrict__ vt, u16* __restrict__ attn) {
  __shared__ __attribute__((aligned(16))) char K_lds[2][2][8192]; // [kvh][buf]
  __shared__ __attribute__((aligned(16))) char V_lds[2][8192];    // [kvh]
  __shared__ float Ml[2][32];                   // [wq][q] kv-half-1 l-sums
  const int tid = threadIdx.x, lane = tid & 63, w = tid >> 6;   // w = 0..3
  const int lo = lane & 31, hi5 = lane >> 5;
  const int wq = w & 1;                         // q 32-row subtile of block
  const int kvh = w >> 1;                       // kv half
  // XCD-aware mapping: 2 heads per XCD (R6/R8-verified geometry)
  const int wg = blockIdx.x;                    // 0..1023
  const int xcd = wg & 7, idx = wg >> 3;        // idx 0..127
  const int bh = xcd * 2 + (idx >> 6), qb = idx & 63;
  const int q0 = qb * 64 + wq * 32;             // wave's 32 q-rows
  const size_t hb = (size_t)bh * 4096 * 64;
  const u16* kbase = k + hb;
  const u16* vbase = vt + hb;                   // [64 d][4096 s] per head
  // Q as B-operand frags: lane holds Q[q0+lo][ds*16 + hi5*8 + j]
  bf16x8 qf[4];
#pragma unroll
  for (int ds = 0; ds < 4; ++ds)
    qf[ds] = ld8(q + hb + (size_t)(q0 + lo) * 64 + ds * 16 + hi5 * 8);

  f32x16 acc[2] = {};                 // O[q=crow(r,hi5)][dv=ds2*32+lo]
  float lrun = 0.f;                   // per-lane HALF-row partial
  bf16x8 pa[4];                       // packed P of the in-flight tile
  bf16x8 vfr[8];                      // V frags of the in-flight tile

  const int srow8 = lane >> 3;        // 0..7: row within 8-row chunk
  const int sx    = (lane & 7) ^ srow8;  // pre-swizzled 16B slot
  const int schunk = wq * 4;          // this wave stages chunks {schunk..+3}

  // K chunk c (0..7): LDS row R=c*8+srow8 (kv), slot sx -> K[kv0+R][sx*8 d]
#define STAGE_K(buf, kv0)                                                     \
  {                                                                           \
    char* kb_l = K_lds[kvh][buf];                                             \
    _Pragma("unroll")                                                         \
    for (int i = 0; i < 4; ++i) {                                             \
      const int c = schunk + i;           /* 0..7, wave-uniform */            \
      gload16(kb_l + c * 1024,                                                \
              kbase + (size_t)((kv0) + c * 8 + srow8) * 64 + sx * 8);         \
    }                                                                         \
  }
  // V chunk c (0..7): LDS row R=c*8+srow8 (d), slot sx -> V^T[R][kv0+sx*8]
#define STAGE_V(kv0)                                                          \
  {                                                                           \
    char* vb_l = V_lds[kvh];                                                  \
    _Pragma("unroll")                                                         \
    for (int i = 0; i < 4; ++i) {                                             \
      const int c = schunk + i;                                               \
      gload16(vb_l + c * 1024,                                                \
              vbase + (size_t)(c * 8 + srow8) * 4096 + (kv0) + sx * 8);       \
    }                                                                         \
  }
  // read V tile (single buffer) into registers
#define VREAD()                                                               \
  {                                                                           \
    const char* vl = V_lds[kvh];                                              \
    _Pragma("unroll")                                                         \
    for (int sl = 0; sl < 4; ++sl)                                            \
      _Pragma("unroll")                                                       \
      for (int ds2 = 0; ds2 < 2; ++ds2) {                                     \
        const int row = ds2 * 32 + lo;                                        \
        vfr[sl * 2 + ds2] = ld8(vl + row * 128 +                              \
                                ((sl * 32 + hi5 * 16) ^ ((row & 7) << 4)));   \
      }                                                                       \
  }
  // pack 8 consecutive p-values (f32, kv-slice) into a PV A-frag
#define PACK(stv, ksl, dst)                                                   \
  {                                                                           \
    u32 A0 = cvtpk(stv[8 * ksl + 0], stv[8 * ksl + 1]);                       \
    u32 A1 = cvtpk(stv[8 * ksl + 2], stv[8 * ksl + 3]);                       \
    u32 B0 = cvtpk(stv[8 * ksl + 4], stv[8 * ksl + 5]);                       \
    u32 B1 = cvtpk(stv[8 * ksl + 6], stv[8 * ksl + 7]);                       \
    asm("v_permlane32_swap_b32 %0, %1" : "+v"(A0), "+v"(B0));                 \
    asm("v_permlane32_swap_b32 %0, %1" : "+v"(A1), "+v"(B1));                 \
    u32x4 pw; pw.x = A0; pw.y = A1; pw.z = B0; pw.w = B1;                     \
    dst = __builtin_bit_cast(bf16x8, pw);                                     \
  }
  // PV of the in-flight tile: pure-register 8-MFMA cluster
#define PVSTEP()                                                              \
  {                                                                           \
    __builtin_amdgcn_s_setprio(1);                                            \
    _Pragma("unroll")                                                         \
    for (int sl = 0; sl < 4; ++sl)                                            \
      _Pragma("unroll")                                                       \
      for (int ds2 = 0; ds2 < 2; ++ds2)                                       \
        acc[ds2] = __builtin_amdgcn_mfma_f32_32x32x16_bf16(                   \
            pa[sl], vfr[sl * 2 + ds2], acc[ds2], 0, 0, 0);                    \
    __builtin_amdgcn_s_setprio(0);                                            \
  }
  // QK of tile in K buf CUR -> st0, st1 (8 MFMA)
#define QKSTEP(CUR, S0, S1)                                                   \
  {                                                                           \
    const char* kl = K_lds[kvh][CUR];                                         \
    S0 = fz16(); S1 = fz16();                                                 \
    __builtin_amdgcn_s_setprio(1);                                            \
    _Pragma("unroll")                                                         \
    for (int ds = 0; ds < 4; ++ds) {                                          \
      const int r0 = lo, r1 = 32 + lo;                                        \
      const int col = ds * 32 + hi5 * 16;                                     \
      bf16x8 kf0 = ld8(kl + r0 * 128 + (col ^ ((r0 & 7) << 4)));              \
      bf16x8 kf1 = ld8(kl + r1 * 128 + (col ^ ((r1 & 7) << 4)));              \
      S0 = __builtin_amdgcn_mfma_f32_32x32x16_bf16(kf0, qf[ds], S0, 0, 0, 0); \
      S1 = __builtin_amdgcn_mfma_f32_32x32x16_bf16(kf1, qf[ds], S1, 0, 0, 0); \
    }                                                                         \
    __builtin_amdgcn_s_setprio(0);                                            \
  }
  // exp2 in place + l accumulate + pack into pa[0..3]
#define SMPACK(S0, S1)                                                        \
  {                                                                           \
    f32x2 lt; lt.x = 0.f; lt.y = 0.f;                                         \
    _Pragma("unroll")                                                         \
    for (int i = 0; i < 8; ++i) {                                             \
      S0[2*i]   = __builtin_amdgcn_exp2f(S0[2*i]);                            \
      S0[2*i+1] = __builtin_amdgcn_exp2f(S0[2*i+1]);                          \
      f32x2 e0; e0.x = S0[2*i]; e0.y = S0[2*i+1]; lt += e0;                   \
      S1[2*i]   = __builtin_amdgcn_exp2f(S1[2*i]);                            \
      S1[2*i+1] = __builtin_amdgcn_exp2f(S1[2*i+1]);                          \
      f32x2 e1; e1.x = S1[2*i]; e1.y = S1[2*i+1]; lt += e1;                   \
    }                                                                         \
    lrun += lt.x + lt.y;                                                      \
    PACK(S0, 0, pa[0]); PACK(S0, 1, pa[1]);                                   \
    PACK(S1, 0, pa[2]); PACK(S1, 1, pa[3]);                                   \
  }

  const int kvbase = kvh * 2048;
  f32x16 st0, st1;
  // ---- prologue: stage tile 0; iteration 0 (no PV)
  STAGE_K(0, kvbase);
  STAGE_V(kvbase);
  __syncthreads();                    // tile 0 landed
  VREAD();                            // V(0) -> regs
  __syncthreads();                    // 2a: all waves done with V_lds
  STAGE_K(1, kvbase + 64);
  STAGE_V(kvbase + 64);
  QKSTEP(0, st0, st1);
  SMPACK(st0, st1);
  __syncthreads();                    // 2b: tile 1 landed; K(0) reads done

  // ---- steady state
  for (int t = 1; t < 32; ++t) {
    const int cur = t & 1;
    PVSTEP();                         // PV(t-1): consumes pa, vfr
    VREAD();                          // V(t) -> regs (staged at t-1)
    __syncthreads();                  // 2a: all waves done with V_lds
    if (t < 31) {
      STAGE_K(cur ^ 1, kvbase + (t + 1) * 64);
      STAGE_V(kvbase + (t + 1) * 64);
    }
    QKSTEP(cur, st0, st1);
    SMPACK(st0, st1);
    __syncthreads();                  // 2b: t+1 landed; K(t) reads done
  }
  PVSTEP();                           // tile 31

  // ---- complete per-row l sum across lane halves BEFORE combine
  lrun += __shfl_xor(lrun, 32);
  __syncthreads();                    // all LDS traffic done before overlay
  // ---- combine the two kv-halves through LDS, then write [S,B,E] bf16
  float* Ob = (float*)K_lds;          // [wq][32 q][64 d] f32 = 16 KB overlay
  if (w >= 2) {                       // kv-half 1 publishes its state
#pragma unroll
    for (int r = 0; r < 16; ++r) {
      const int crow = (r & 3) + 8 * (r >> 2) + 4 * hi5;
#pragma unroll
      for (int ds2 = 0; ds2 < 2; ++ds2)
        Ob[(wq * 32 + crow) * 64 + ds2 * 32 + lo] = acc[ds2][r];
    }
    if (hi5 == 0) Ml[wq][lo] = lrun;
  }
  __syncthreads();
  if (w < 2) {                        // kv-half 0 merges and writes out
    const float linv = 1.0f / (lrun + Ml[wq][lo]);  // shift-free merge
    const int b = bh >> 3, h = bh & 7;
#pragma unroll
    for (int r = 0; r < 16; ++r) {
      const int crow = (r & 3) + 8 * (r >> 2) + 4 * hi5;
      const float ivR = __shfl(linv, crow);
      const int s = q0 + crow;
#pragma unroll
      for (int ds2 = 0; ds2 < 2; ++ds2) {
        const float ob = Ob[(wq * 32 + crow) * 64 + ds2 * 32 + lo];
        attn[(size_t)(s * 2 + b) * 512 + h * 64 + ds2 * 32 + lo] =
            f2bf((acc[ds2][r] + ob) * ivR);
      }
    }
  }
#undef STAGE_K
#undef STAGE_V
#undef VREAD
#undef PACK
#undef PVSTEP
#undef QKSTEP
#undef SMPACK
}

// ---------------- launcher ------------------------------------------------
extern "C" void kernel_launch(void* const* d_in, const int* in_sizes, int n_in,
                              void* d_out, int out_size, void* d_ws, size_t ws_size,
                              hipStream_t stream) {
  const float* x     = (const float*)d_in[0];
  const float* w_in  = (const float*)d_in[1];
  const float* b_in  = (const float*)d_in[2];
  const float* w_out = (const float*)d_in[3];
  const float* b_out = (const float*)d_in[4];
  float* out = (float*)d_out;
  char* ws = (char*)d_ws;
  // layout (bytes):
  u16* xb  = (u16*)(ws);               // 8,388,608   x bf16 [8192][512]
  u16* wb  = (u16*)(ws + 8388608);     // 1,572,864   in_proj_w bf16 [1536][512]
  u16* ob  = (u16*)(ws + 9961472);     //   524,288   out_w bf16 [512][512]
  u16* qb  = (u16*)(ws + 10485760);    // 8,388,608   q bf16 [16][4096][64] (pre-scaled)
  u16* kb  = (u16*)(ws + 18874368);    // 8,388,608   k
  u16* vb  = (u16*)(ws + 27262976);    // 8,388,608   v
  u16* vtb = (u16*)(ws + 35651584);    // 8,388,608   v^T [16][64][4096]
  u16* attn = xb;                      // alias: xb fully consumed by gemm<0>

  cvt_kernel<<<5120, 256, 0, stream>>>(x, w_in, w_out, xb, wb, ob);
  gemm_bt<0><<<dim3(64, 12), 256, 0, stream>>>(xb, wb, b_in, qb, kb, vb,
                                               nullptr, 8192, 1536, 512);
  transpose_v<<<dim3(64, 16), 256, 0, stream>>>(vb, vtb);
  fa_kernel<<<1024, 256, 0, stream>>>(qb, kb, vtb, attn);
  gemm_bt<1><<<dim3(64, 4), 256, 0, stream>>>(attn, ob, b_out, nullptr, nullptr,
                                              nullptr, out, 8192, 512, 512);
}

// Round 19
// 130.803 us; speedup vs baseline: 1.1441x; 1.1441x over previous
//
#include <hip/hip_runtime.h>

typedef unsigned short u16;
typedef unsigned int   u32;
typedef short bf16x8 __attribute__((ext_vector_type(8)));
typedef float f32x2  __attribute__((ext_vector_type(2)));
typedef float f32x4  __attribute__((ext_vector_type(4)));
typedef float f32x16 __attribute__((ext_vector_type(16)));
typedef u32   u32x4  __attribute__((ext_vector_type(4)));

#define QK_SCALE 0.18033688011112042f   // 0.125 * log2(e): fold softmax exp2 into q

__device__ __forceinline__ u16 f2bf(float f) {
  u32 u = __builtin_bit_cast(u32, f);
  u = (u + 0x7FFFu + ((u >> 16) & 1u)) >> 16;   // RNE
  return (u16)u;
}

__device__ __forceinline__ u32 cvtpk(float lo, float hi) {
  u32 r;
  asm("v_cvt_pk_bf16_f32 %0, %1, %2" : "=v"(r) : "v"(lo), "v"(hi));
  return r;
}

__device__ __forceinline__ void gload16(void* lds, const void* g) {
  __builtin_amdgcn_global_load_lds(
      (const __attribute__((address_space(1))) u32*)g,
      (__attribute__((address_space(3))) u32*)lds, 16, 0, 0);
}

__device__ __forceinline__ bf16x8 ld8(const void* p) {
  return *(const bf16x8*)p;
}

// ---------------- kernel 1: fp32 -> bf16 convert (x, in_proj_w, out_w) ----
__global__ __launch_bounds__(256) void cvt_kernel(
    const float* __restrict__ x, const float* __restrict__ w1,
    const float* __restrict__ w2,
    u16* __restrict__ xb, u16* __restrict__ wb, u16* __restrict__ ob) {
  int i = blockIdx.x * 256 + threadIdx.x;      // one float4 per thread
  const float* src; u16* dst; int off;
  if (i < 1048576)            { src = x;  dst = xb; off = i; }
  else if (i < 1048576+196608){ src = w1; dst = wb; off = i - 1048576; }
  else                        { src = w2; dst = ob; off = i - 1245184; }
  float4 v = ((const float4*)src)[off];
  ushort4 o;
  o.x = f2bf(v.x); o.y = f2bf(v.y); o.z = f2bf(v.z); o.w = f2bf(v.w);
  ((ushort4*)dst)[off] = o;
}

// ---------------- kernel 2/5: bf16 GEMM  C = A * B^T  (+bias) -------------
// Tile: 128(M) x (NI*32)(N), BK=64, 4 waves (2x2), wave = 64 x (NI*16).
// NI=4 -> BN=128 (qkv GEMM, verified); NI=2 -> BN=64 (out-proj: doubles the
// grid for the small-N case, 256 -> 512 blocks, and halves acc VGPR so the
// hardware co-schedules more waves/SIMD on this short-K latency-bound GEMM).
// K-accumulation order per output element identical for both NI.
template<int MODE, int NI>
__global__ __launch_bounds__(256, 2) void gemm_bt(
    const u16* __restrict__ A, const u16* __restrict__ Bm,
    const float* __restrict__ bias,
    u16* __restrict__ q_out, u16* __restrict__ k_out, u16* __restrict__ v_out,
    float* __restrict__ f_out, int M, int N, int K) {
  __shared__ __attribute__((aligned(16))) u16 As[128 * 64];
  __shared__ __attribute__((aligned(16))) u16 Bs[NI * 32 * 64];
  const int tid = threadIdx.x, lane = tid & 63, w = tid >> 6;
  const int wm = w >> 1, wn = w & 1;
  const int lo = lane & 15, hi = lane >> 4;
  const int m0 = blockIdx.x * 128, n0 = blockIdx.y * (NI * 32);
  f32x4 acc[4][NI] = {};
  const int srow = lane >> 3;                   // row within 8-row chunk
  const int skc  = (lane & 7) ^ srow;           // pre-swizzled source chunk
  const int nk = K >> 6;
  for (int kt = 0; kt < nk; ++kt) {
    __syncthreads();                            // WAR on LDS
    const int k0 = kt * 64;
#pragma unroll
    for (int c = 0; c < 4; ++c) {
      const int ch = w * 4 + c;                 // 0..15, wave-uniform
      const int row = ch * 8 + srow;
      gload16((char*)As + ch * 1024, A + (size_t)(m0 + row) * K + k0 + skc * 8);
    }
#pragma unroll
    for (int c = 0; c < NI; ++c) {
      const int ch = w * NI + c;                // 0..4*NI-1, wave-uniform
      const int row = ch * 8 + srow;
      gload16((char*)Bs + ch * 1024, Bm + (size_t)(n0 + row) * K + k0 + skc * 8);
    }
    __syncthreads();                            // vmcnt(0) drained by compiler
#pragma unroll
    for (int kk = 0; kk < 2; ++kk) {
      bf16x8 af[4], bfr[NI];
#pragma unroll
      for (int mi = 0; mi < 4; ++mi) {
        const int row = wm * 64 + mi * 16 + lo;
        const int kc = kk * 4 + hi;
        af[mi] = ld8((const char*)As + row * 128 + ((kc ^ (row & 7)) << 4));
      }
#pragma unroll
      for (int ni = 0; ni < NI; ++ni) {
        const int row = wn * (NI * 16) + ni * 16 + lo;
        const int kc = kk * 4 + hi;
        bfr[ni] = ld8((const char*)Bs + row * 128 + ((kc ^ (row & 7)) << 4));
      }
#pragma unroll
      for (int mi = 0; mi < 4; ++mi)
#pragma unroll
        for (int ni = 0; ni < NI; ++ni)
          acc[mi][ni] = __builtin_amdgcn_mfma_f32_16x16x32_bf16(
              af[mi], bfr[ni], acc[mi][ni], 0, 0, 0);
    }
  }
  // epilogue
#pragma unroll
  for (int mi = 0; mi < 4; ++mi)
#pragma unroll
    for (int ni = 0; ni < NI; ++ni) {
      const int gn = n0 + wn * (NI * 16) + ni * 16 + lo;
      const float bv = bias[gn];
#pragma unroll
      for (int r = 0; r < 4; ++r) {
        const int gm = m0 + wm * 64 + mi * 16 + hi * 4 + r;
        float val = acc[mi][ni][r] + bv;
        if (MODE == 0) {
          const int s = gm >> 1, b = gm & 1;
          const int sec = gn >> 9, e = gn & 511;
          const int h = e >> 6, d = e & 63;
          const size_t o = (((size_t)(b * 8 + h) * 4096 + s) << 6) + d;
          if (sec == 0)      q_out[o] = f2bf(val * QK_SCALE);
          else if (sec == 1) k_out[o] = f2bf(val);
          else               v_out[o] = f2bf(val);
        } else {
          f_out[(size_t)gm * N + gn] = val;
        }
      }
    }
}

// ---------------- kernel 3: V [BH][S][64] -> V^T [BH][64][S] --------------
__global__ __launch_bounds__(256) void transpose_v(
    const u16* __restrict__ v, u16* __restrict__ vt) {
  __shared__ __attribute__((aligned(16))) u16 T[64 * 72];
  const int bh = blockIdx.y, s0 = blockIdx.x * 64;
  const int t = threadIdx.x;
#pragma unroll
  for (int i = 0; i < 2; ++i) {
    const int idx = t + i * 256;                // 0..511
    const int row = idx >> 3, c = idx & 7;
    uint4 d = *(const uint4*)(v + ((size_t)bh * 4096 + s0 + row) * 64 + c * 8);
    *(uint4*)(&T[row * 72 + c * 8]) = d;
  }
  __syncthreads();
#pragma unroll
  for (int i = 0; i < 2; ++i) {
    const int idx = t + i * 256;
    const int dcol = idx >> 3, sc = idx & 7;
    u16 tmp[8];
#pragma unroll
    for (int j = 0; j < 8; ++j) tmp[j] = T[(sc * 8 + j) * 72 + dcol];
    *(uint4*)(vt + ((size_t)bh * 64 + dcol) * 4096 + s0 + sc * 8) = *(const uint4*)tmp;
  }
}

// ---------------- kernel 4: flash attention, T15 software pipeline --------
// R11/R16 VERIFIED (88 us): split-K=2, 2 q-subtiles/wave, KVBLK=64,
// grid 512, one-tile-deep pipeline -- pa (packed P) and vfr (V frags) of
// tile t stay in REGISTERS across the barrier; PV(t-1) executes at the TOP
// of iteration t as a pure-register 16-MFMA cluster. exp2 via v_exp_f32.
// Closed levers (each measured, do not retry): more TLP (R6/R9/R14/R17:
// never pays -- staging doubles or barriers re-expose); E/O deep pipeline
// (R12: regalloc re-serializes); V-direct-global (R13: spills at 128-VGPR
// cap); poly exp2 (R15: reassociation folds magic-round to a staircase).
// Max-free softmax (R8-verified): p = exp2(st), shift 0, merge by l-sums.
__global__ __launch_bounds__(256, 2) void fa_kernel(
    const u16* __restrict__ q, const u16* __restrict__ k,
    const u16* __restrict__ vt, u16* __restrict__ attn) {
  // [kvh][buf][ K 8KB | V 8KB ]
  __shared__ __attribute__((aligned(16))) char S_lds[2][2][16384];
  __shared__ float Ml[2][2][32];                // [wq][qt][q] l-sums
  const int tid = threadIdx.x, lane = tid & 63, w = tid >> 6;   // w = 0..3
  const int lo = lane & 31, hi5 = lane >> 5;
  const int wq = w & 1;                         // q 64-row half of block
  const int kvh = w >> 1;                       // kv half
  // XCD-aware mapping: 2 heads per XCD
  const int wg = blockIdx.x;                    // 0..511
  const int xcd = wg & 7, idx = wg >> 3;        // idx 0..63
  const int bh = xcd * 2 + (idx >> 5), qb = idx & 31;
  const int q0 = qb * 128 + wq * 64;            // wave's 64 q-rows
  const size_t hb = (size_t)bh * 4096 * 64;
  const u16* kbase = k + hb;
  const u16* vbase = vt + hb;                   // [64 d][4096 s] per head
  // Q B-operand frags for both 32-q subtiles
  bf16x8 qfA[4], qfB[4];
#pragma unroll
  for (int ds = 0; ds < 4; ++ds) {
    qfA[ds] = ld8(q + hb + (size_t)(q0 + lo) * 64 + ds * 16 + hi5 * 8);
    qfB[ds] = ld8(q + hb + (size_t)(q0 + 32 + lo) * 64 + ds * 16 + hi5 * 8);
  }

  f32x16 accA[2] = {}, accB[2] = {};  // O[q=crow(r,hi5)][dv=ds2*32+lo]
  float lrunA = 0.f, lrunB = 0.f;     // per-lane HALF-row partials
  bf16x8 paA[4], paB[4];              // packed P of the in-flight tile
  bf16x8 vfr[8];                      // V frags of the in-flight tile

  const int srow8 = lane >> 3;        // 0..7: row within 8-row chunk
  const int sx    = (lane & 7) ^ srow8;  // pre-swizzled 16B slot
  const int schunk = wq * 4;          // this wave stages chunks {schunk..+3}

  // K chunk c (0..7): LDS row R=c*8+srow8 (kv), slot sx -> K[kv0+R][sx*8 d]
  // V chunk c (0..7): LDS row R=c*8+srow8 (d),  slot sx -> V^T[R][kv0+sx*8]
#define STAGE(buf, kv0)                                                       \
  {                                                                           \
    char* kb_l = S_lds[kvh][buf];                                             \
    char* vb_l = kb_l + 8192;                                                 \
    _Pragma("unroll")                                                         \
    for (int i = 0; i < 4; ++i) {                                             \
      const int c = schunk + i;           /* 0..7, wave-uniform */            \
      gload16(kb_l + c * 1024,                                                \
              kbase + (size_t)((kv0) + c * 8 + srow8) * 64 + sx * 8);         \
      gload16(vb_l + c * 1024,                                                \
              vbase + (size_t)(c * 8 + srow8) * 4096 + (kv0) + sx * 8);       \
    }                                                                         \
  }

  // pack 8 consecutive p-values (f32, kv-slice) into a PV A-frag
#define PACK(stv, ksl, pa)                                                    \
  {                                                                           \
    u32 A0 = cvtpk(stv[8 * ksl + 0], stv[8 * ksl + 1]);                       \
    u32 A1 = cvtpk(stv[8 * ksl + 2], stv[8 * ksl + 3]);                       \
    u32 B0 = cvtpk(stv[8 * ksl + 4], stv[8 * ksl + 5]);                       \
    u32 B1 = cvtpk(stv[8 * ksl + 6], stv[8 * ksl + 7]);                       \
    asm("v_permlane32_swap_b32 %0, %1" : "+v"(A0), "+v"(B0));                 \
    asm("v_permlane32_swap_b32 %0, %1" : "+v"(A1), "+v"(B1));                 \
    u32x4 pw; pw.x = A0; pw.y = A1; pw.z = B0; pw.w = B1;                     \
    pa = __builtin_bit_cast(bf16x8, pw);                                      \
  }

  // PV of the in-flight tile: pure-register 16-MFMA cluster
#define PVSTEP()                                                              \
  {                                                                           \
    __builtin_amdgcn_s_setprio(1);                                            \
    _Pragma("unroll")                                                         \
    for (int sl = 0; sl < 4; ++sl)                                            \
      _Pragma("unroll")                                                       \
      for (int ds2 = 0; ds2 < 2; ++ds2) {                                     \
        accA[ds2] = __builtin_amdgcn_mfma_f32_32x32x16_bf16(                  \
            paA[sl], vfr[sl * 2 + ds2], accA[ds2], 0, 0, 0);                  \
        accB[ds2] = __builtin_amdgcn_mfma_f32_32x32x16_bf16(                  \
            paB[sl], vfr[sl * 2 + ds2], accB[ds2], 0, 0, 0);                  \
      }                                                                       \
    __builtin_amdgcn_s_setprio(0);                                            \
  }

  // QK(tile in buf CUR) -> exp2 -> pack into pa; vread V into vfr
#define COMPUTE(CUR)                                                          \
  {                                                                           \
    const char* kl = S_lds[kvh][CUR];                                         \
    const char* vl = kl + 8192;                                               \
    f32x16 stA0 = {}, stA1 = {}, stB0 = {}, stB1 = {};                        \
    __builtin_amdgcn_s_setprio(1);                                            \
    _Pragma("unroll")                                                         \
    for (int ds = 0; ds < 4; ++ds) {                                          \
      const int r0 = lo, r1 = 32 + lo;                                        \
      const int col = ds * 32 + hi5 * 16;                                     \
      bf16x8 kf0 = ld8(kl + r0 * 128 + (col ^ ((r0 & 7) << 4)));              \
      bf16x8 kf1 = ld8(kl + r1 * 128 + (col ^ ((r1 & 7) << 4)));              \
      stA0 = __builtin_amdgcn_mfma_f32_32x32x16_bf16(kf0, qfA[ds], stA0,0,0,0);\
      stB0 = __builtin_amdgcn_mfma_f32_32x32x16_bf16(kf0, qfB[ds], stB0,0,0,0);\
      stA1 = __builtin_amdgcn_mfma_f32_32x32x16_bf16(kf1, qfA[ds], stA1,0,0,0);\
      stB1 = __builtin_amdgcn_mfma_f32_32x32x16_bf16(kf1, qfB[ds], stB1,0,0,0);\
    }                                                                         \
    __builtin_amdgcn_s_setprio(0);                                            \
    _Pragma("unroll")                                                         \
    for (int sl = 0; sl < 4; ++sl)                                            \
      _Pragma("unroll")                                                       \
      for (int ds2 = 0; ds2 < 2; ++ds2) {                                     \
        const int row = ds2 * 32 + lo;                                        \
        vfr[sl * 2 + ds2] = ld8(vl + row * 128 +                              \
                                ((sl * 32 + hi5 * 16) ^ ((row & 7) << 4)));   \
      }                                                                       \
    f32x2 ltA; ltA.x = 0.f; ltA.y = 0.f;                                      \
    f32x2 ltB; ltB.x = 0.f; ltB.y = 0.f;                                      \
    _Pragma("unroll")                                                         \
    for (int i = 0; i < 8; ++i) {                                             \
      stA0[2*i]   = __builtin_amdgcn_exp2f(stA0[2*i]);                        \
      stA0[2*i+1] = __builtin_amdgcn_exp2f(stA0[2*i+1]);                      \
      f32x2 a0; a0.x = stA0[2*i]; a0.y = stA0[2*i+1]; ltA += a0;              \
      stA1[2*i]   = __builtin_amdgcn_exp2f(stA1[2*i]);                        \
      stA1[2*i+1] = __builtin_amdgcn_exp2f(stA1[2*i+1]);                      \
      f32x2 a1; a1.x = stA1[2*i]; a1.y = stA1[2*i+1]; ltA += a1;              \
      stB0[2*i]   = __builtin_amdgcn_exp2f(stB0[2*i]);                        \
      stB0[2*i+1] = __builtin_amdgcn_exp2f(stB0[2*i+1]);                      \
      f32x2 b0; b0.x = stB0[2*i]; b0.y = stB0[2*i+1]; ltB += b0;              \
      stB1[2*i]   = __builtin_amdgcn_exp2f(stB1[2*i]);                        \
      stB1[2*i+1] = __builtin_amdgcn_exp2f(stB1[2*i+1]);                      \
      f32x2 b1; b1.x = stB1[2*i]; b1.y = stB1[2*i+1]; ltB += b1;              \
    }                                                                         \
    lrunA += ltA.x + ltA.y;                                                   \
    lrunB += ltB.x + ltB.y;                                                   \
    PACK(stA0, 0, paA[0]); PACK(stA0, 1, paA[1]);                             \
    PACK(stA1, 0, paA[2]); PACK(stA1, 1, paA[3]);                             \
    PACK(stB0, 0, paB[0]); PACK(stB0, 1, paB[1]);                             \
    PACK(stB1, 0, paB[2]); PACK(stB1, 1, paB[3]);                             \
  }

  const int kvbase = kvh * 2048;
  // ---- pipeline prologue: stage 0,1; compute tile 0 (no PV yet)
  STAGE(0, kvbase);
  __syncthreads();                    // tile 0 ready
  STAGE(1, kvbase + 64);
  COMPUTE(0);
  __syncthreads();                    // tile 1 ready; tile 0 reads done

  // ---- steady state: PV(t-1) [regs] || STAGE(t+1) || QK/exp2/pack(t)
  for (int t = 1; t < 32; ++t) {
    const int cur = t & 1;
    if (t < 31) STAGE(cur ^ 1, kvbase + (t + 1) * 64);
    PVSTEP();                         // tile t-1, pure registers
    if (cur) { COMPUTE(1); } else { COMPUTE(0); }
    __syncthreads();                  // tile t+1 landed; tile t reads done
  }
  PVSTEP();                           // tile 31

  // ---- complete per-row l sums across lane halves BEFORE combine
  lrunA += __shfl_xor(lrunA, 32);
  lrunB += __shfl_xor(lrunB, 32);
  // ---- combine the two kv-halves through LDS, then write [S,B,E] bf16
  // Ob overlays staging LDS (safe: loop-final barrier drained all reads)
  float* Ob = (float*)S_lds;          // [(wq*2+qt)*32 + q][64 d] f32 = 32 KB
  if (w >= 2) {                       // kv-half 1 publishes its state
#pragma unroll
    for (int r = 0; r < 16; ++r) {
      const int crow = (r & 3) + 8 * (r >> 2) + 4 * hi5;
#pragma unroll
      for (int ds2 = 0; ds2 < 2; ++ds2) {
        Ob[((wq * 2 + 0) * 32 + crow) * 64 + ds2 * 32 + lo] = accA[ds2][r];
        Ob[((wq * 2 + 1) * 32 + crow) * 64 + ds2 * 32 + lo] = accB[ds2][r];
      }
    }
    if (hi5 == 0) { Ml[wq][0][lo] = lrunA; Ml[wq][1][lo] = lrunB; }
  }
  __syncthreads();
  if (w < 2) {                        // kv-half 0 merges and writes out
    const float linvA = 1.0f / (lrunA + Ml[wq][0][lo]);
    const float linvB = 1.0f / (lrunB + Ml[wq][1][lo]);
    const int b = bh >> 3, h = bh & 7;
#pragma unroll
    for (int r = 0; r < 16; ++r) {
      const int crow = (r & 3) + 8 * (r >> 2) + 4 * hi5;
      const float ivA = __shfl(linvA, crow);
      const float ivB = __shfl(linvB, crow);
      const int sA = q0 + crow, sB = q0 + 32 + crow;
#pragma unroll
      for (int ds2 = 0; ds2 < 2; ++ds2) {
        const float oA = Ob[((wq * 2 + 0) * 32 + crow) * 64 + ds2 * 32 + lo];
        const float oB = Ob[((wq * 2 + 1) * 32 + crow) * 64 + ds2 * 32 + lo];
        attn[(size_t)(sA * 2 + b) * 512 + h * 64 + ds2 * 32 + lo] =
            f2bf((accA[ds2][r] + oA) * ivA);
        attn[(size_t)(sB * 2 + b) * 512 + h * 64 + ds2 * 32 + lo] =
            f2bf((accB[ds2][r] + oB) * ivB);
      }
    }
  }
#undef STAGE
#undef PACK
#undef PVSTEP
#undef COMPUTE
}

// ---------------- launcher ------------------------------------------------
extern "C" void kernel_launch(void* const* d_in, const int* in_sizes, int n_in,
                              void* d_out, int out_size, void* d_ws, size_t ws_size,
                              hipStream_t stream) {
  const float* x     = (const float*)d_in[0];
  const float* w_in  = (const float*)d_in[1];
  const float* b_in  = (const float*)d_in[2];
  const float* w_out = (const float*)d_in[3];
  const float* b_out = (const float*)d_in[4];
  float* out = (float*)d_out;
  char* ws = (char*)d_ws;
  // layout (bytes):
  u16* xb  = (u16*)(ws);               // 8,388,608   x bf16 [8192][512]
  u16* wb  = (u16*)(ws + 8388608);     // 1,572,864   in_proj_w bf16 [1536][512]
  u16* ob  = (u16*)(ws + 9961472);     //   524,288   out_w bf16 [512][512]
  u16* qb  = (u16*)(ws + 10485760);    // 8,388,608   q bf16 [16][4096][64] (pre-scaled)
  u16* kb  = (u16*)(ws + 18874368);    // 8,388,608   k
  u16* vb  = (u16*)(ws + 27262976);    // 8,388,608   v
  u16* vtb = (u16*)(ws + 35651584);    // 8,388,608   v^T [16][64][4096]
  u16* attn = xb;                      // alias: xb fully consumed by gemm<0>

  cvt_kernel<<<5120, 256, 0, stream>>>(x, w_in, w_out, xb, wb, ob);
  gemm_bt<0, 4><<<dim3(64, 12), 256, 0, stream>>>(xb, wb, b_in, qb, kb, vb,
                                                  nullptr, 8192, 1536, 512);
  transpose_v<<<dim3(64, 16), 256, 0, stream>>>(vb, vtb);
  fa_kernel<<<512, 256, 0, stream>>>(qb, kb, vtb, attn);
  gemm_bt<1, 2><<<dim3(64, 8), 256, 0, stream>>>(attn, ob, b_out, nullptr,
                                                 nullptr, nullptr, out,
                                                 8192, 512, 512);
}

// Round 20
// 129.507 us; speedup vs baseline: 1.1555x; 1.0100x over previous
//
#include <hip/hip_runtime.h>

typedef unsigned short u16;
typedef unsigned int   u32;
typedef short bf16x8 __attribute__((ext_vector_type(8)));
typedef float f32x2  __attribute__((ext_vector_type(2)));
typedef float f32x4  __attribute__((ext_vector_type(4)));
typedef float f32x16 __attribute__((ext_vector_type(16)));
typedef u32   u32x4  __attribute__((ext_vector_type(4)));

#define QK_SCALE 0.18033688011112042f   // 0.125 * log2(e): fold softmax exp2 into q

__device__ __forceinline__ u16 f2bf(float f) {
  u32 u = __builtin_bit_cast(u32, f);
  u = (u + 0x7FFFu + ((u >> 16) & 1u)) >> 16;   // RNE
  return (u16)u;
}

__device__ __forceinline__ u32 cvtpk(float lo, float hi) {
  u32 r;
  asm("v_cvt_pk_bf16_f32 %0, %1, %2" : "=v"(r) : "v"(lo), "v"(hi));
  return r;
}

__device__ __forceinline__ void gload16(void* lds, const void* g) {
  __builtin_amdgcn_global_load_lds(
      (const __attribute__((address_space(1))) u32*)g,
      (__attribute__((address_space(3))) u32*)lds, 16, 0, 0);
}

__device__ __forceinline__ bf16x8 ld8(const void* p) {
  return *(const bf16x8*)p;
}

// ---------------- kernel 1: fp32 -> bf16 convert (x, in_proj_w, out_w) ----
__global__ __launch_bounds__(256) void cvt_kernel(
    const float* __restrict__ x, const float* __restrict__ w1,
    const float* __restrict__ w2,
    u16* __restrict__ xb, u16* __restrict__ wb, u16* __restrict__ ob) {
  int i = blockIdx.x * 256 + threadIdx.x;      // one float4 per thread
  const float* src; u16* dst; int off;
  if (i < 1048576)            { src = x;  dst = xb; off = i; }
  else if (i < 1048576+196608){ src = w1; dst = wb; off = i - 1048576; }
  else                        { src = w2; dst = ob; off = i - 1245184; }
  float4 v = ((const float4*)src)[off];
  ushort4 o;
  o.x = f2bf(v.x); o.y = f2bf(v.y); o.z = f2bf(v.z); o.w = f2bf(v.w);
  ((ushort4*)dst)[off] = o;
}

// ---------------- kernel 2/4: bf16 GEMM  C = A * B^T  (+bias) -------------
// Tile: 128(M) x (NI*32)(N), BK=64, 4 waves (2x2), wave = 64 x (NI*16).
// NI=4 -> BN=128 (qkv GEMM); NI=2 -> BN=64 (out-proj: doubles the grid for
// the small-N case and halves acc VGPR on this short-K latency-bound GEMM).
// MODE 0 epilogue scatters q/k per-head [BH][S][D] and V TRANSPOSED
// directly into [BH][D][S] (fuses the former transpose_v kernel; stores
// were already scalar, only the address map changes).
template<int MODE, int NI>
__global__ __launch_bounds__(256, 2) void gemm_bt(
    const u16* __restrict__ A, const u16* __restrict__ Bm,
    const float* __restrict__ bias,
    u16* __restrict__ q_out, u16* __restrict__ k_out, u16* __restrict__ v_out,
    float* __restrict__ f_out, int M, int N, int K) {
  __shared__ __attribute__((aligned(16))) u16 As[128 * 64];
  __shared__ __attribute__((aligned(16))) u16 Bs[NI * 32 * 64];
  const int tid = threadIdx.x, lane = tid & 63, w = tid >> 6;
  const int wm = w >> 1, wn = w & 1;
  const int lo = lane & 15, hi = lane >> 4;
  const int m0 = blockIdx.x * 128, n0 = blockIdx.y * (NI * 32);
  f32x4 acc[4][NI] = {};
  const int srow = lane >> 3;                   // row within 8-row chunk
  const int skc  = (lane & 7) ^ srow;           // pre-swizzled source chunk
  const int nk = K >> 6;
  for (int kt = 0; kt < nk; ++kt) {
    __syncthreads();                            // WAR on LDS
    const int k0 = kt * 64;
#pragma unroll
    for (int c = 0; c < 4; ++c) {
      const int ch = w * 4 + c;                 // 0..15, wave-uniform
      const int row = ch * 8 + srow;
      gload16((char*)As + ch * 1024, A + (size_t)(m0 + row) * K + k0 + skc * 8);
    }
#pragma unroll
    for (int c = 0; c < NI; ++c) {
      const int ch = w * NI + c;                // 0..4*NI-1, wave-uniform
      const int row = ch * 8 + srow;
      gload16((char*)Bs + ch * 1024, Bm + (size_t)(n0 + row) * K + k0 + skc * 8);
    }
    __syncthreads();                            // vmcnt(0) drained by compiler
#pragma unroll
    for (int kk = 0; kk < 2; ++kk) {
      bf16x8 af[4], bfr[NI];
#pragma unroll
      for (int mi = 0; mi < 4; ++mi) {
        const int row = wm * 64 + mi * 16 + lo;
        const int kc = kk * 4 + hi;
        af[mi] = ld8((const char*)As + row * 128 + ((kc ^ (row & 7)) << 4));
      }
#pragma unroll
      for (int ni = 0; ni < NI; ++ni) {
        const int row = wn * (NI * 16) + ni * 16 + lo;
        const int kc = kk * 4 + hi;
        bfr[ni] = ld8((const char*)Bs + row * 128 + ((kc ^ (row & 7)) << 4));
      }
#pragma unroll
      for (int mi = 0; mi < 4; ++mi)
#pragma unroll
        for (int ni = 0; ni < NI; ++ni)
          acc[mi][ni] = __builtin_amdgcn_mfma_f32_16x16x32_bf16(
              af[mi], bfr[ni], acc[mi][ni], 0, 0, 0);
    }
  }
  // epilogue
#pragma unroll
  for (int mi = 0; mi < 4; ++mi)
#pragma unroll
    for (int ni = 0; ni < NI; ++ni) {
      const int gn = n0 + wn * (NI * 16) + ni * 16 + lo;
      const float bv = bias[gn];
#pragma unroll
      for (int r = 0; r < 4; ++r) {
        const int gm = m0 + wm * 64 + mi * 16 + hi * 4 + r;
        float val = acc[mi][ni][r] + bv;
        if (MODE == 0) {
          const int s = gm >> 1, b = gm & 1;
          const int sec = gn >> 9, e = gn & 511;
          const int h = e >> 6, d = e & 63;
          const int bh = b * 8 + h;
          if (sec == 0)
            q_out[(((size_t)bh * 4096 + s) << 6) + d] = f2bf(val * QK_SCALE);
          else if (sec == 1)
            k_out[(((size_t)bh * 4096 + s) << 6) + d] = f2bf(val);
          else  // V written TRANSPOSED: [BH][64 d][4096 s] (fa's layout)
            v_out[((size_t)bh * 64 + d) * 4096 + s] = f2bf(val);
        } else {
          f_out[(size_t)gm * N + gn] = val;
        }
      }
    }
}

// ---------------- kernel 3: flash attention, T15 software pipeline --------
// R11/R16 VERIFIED (88 us): split-K=2, 2 q-subtiles/wave, KVBLK=64,
// grid 512, one-tile-deep pipeline -- pa (packed P) and vfr (V frags) of
// tile t stay in REGISTERS across the barrier; PV(t-1) executes at the TOP
// of iteration t as a pure-register 16-MFMA cluster. exp2 via v_exp_f32.
// Closed levers (each measured, do not retry): more TLP (R6/R9/R14/R17:
// never pays -- staging doubles or barriers re-expose); E/O deep pipeline
// (R12: regalloc re-serializes); V-direct-global (R13: spills at 128-VGPR
// cap); poly exp2 (R15: reassociation folds magic-round to a staircase).
// Max-free softmax (R8-verified): p = exp2(st), shift 0, merge by l-sums.
__global__ __launch_bounds__(256, 2) void fa_kernel(
    const u16* __restrict__ q, const u16* __restrict__ k,
    const u16* __restrict__ vt, u16* __restrict__ attn) {
  // [kvh][buf][ K 8KB | V 8KB ]
  __shared__ __attribute__((aligned(16))) char S_lds[2][2][16384];
  __shared__ float Ml[2][2][32];                // [wq][qt][q] l-sums
  const int tid = threadIdx.x, lane = tid & 63, w = tid >> 6;   // w = 0..3
  const int lo = lane & 31, hi5 = lane >> 5;
  const int wq = w & 1;                         // q 64-row half of block
  const int kvh = w >> 1;                       // kv half
  // XCD-aware mapping: 2 heads per XCD
  const int wg = blockIdx.x;                    // 0..511
  const int xcd = wg & 7, idx = wg >> 3;        // idx 0..63
  const int bh = xcd * 2 + (idx >> 5), qb = idx & 31;
  const int q0 = qb * 128 + wq * 64;            // wave's 64 q-rows
  const size_t hb = (size_t)bh * 4096 * 64;
  const u16* kbase = k + hb;
  const u16* vbase = vt + hb;                   // [64 d][4096 s] per head
  // Q B-operand frags for both 32-q subtiles
  bf16x8 qfA[4], qfB[4];
#pragma unroll
  for (int ds = 0; ds < 4; ++ds) {
    qfA[ds] = ld8(q + hb + (size_t)(q0 + lo) * 64 + ds * 16 + hi5 * 8);
    qfB[ds] = ld8(q + hb + (size_t)(q0 + 32 + lo) * 64 + ds * 16 + hi5 * 8);
  }

  f32x16 accA[2] = {}, accB[2] = {};  // O[q=crow(r,hi5)][dv=ds2*32+lo]
  float lrunA = 0.f, lrunB = 0.f;     // per-lane HALF-row partials
  bf16x8 paA[4], paB[4];              // packed P of the in-flight tile
  bf16x8 vfr[8];                      // V frags of the in-flight tile

  const int srow8 = lane >> 3;        // 0..7: row within 8-row chunk
  const int sx    = (lane & 7) ^ srow8;  // pre-swizzled 16B slot
  const int schunk = wq * 4;          // this wave stages chunks {schunk..+3}

  // K chunk c (0..7): LDS row R=c*8+srow8 (kv), slot sx -> K[kv0+R][sx*8 d]
  // V chunk c (0..7): LDS row R=c*8+srow8 (d),  slot sx -> V^T[R][kv0+sx*8]
#define STAGE(buf, kv0)                                                       \
  {                                                                           \
    char* kb_l = S_lds[kvh][buf];                                             \
    char* vb_l = kb_l + 8192;                                                 \
    _Pragma("unroll")                                                         \
    for (int i = 0; i < 4; ++i) {                                             \
      const int c = schunk + i;           /* 0..7, wave-uniform */            \
      gload16(kb_l + c * 1024,                                                \
              kbase + (size_t)((kv0) + c * 8 + srow8) * 64 + sx * 8);         \
      gload16(vb_l + c * 1024,                                                \
              vbase + (size_t)(c * 8 + srow8) * 4096 + (kv0) + sx * 8);       \
    }                                                                         \
  }

  // pack 8 consecutive p-values (f32, kv-slice) into a PV A-frag
#define PACK(stv, ksl, pa)                                                    \
  {                                                                           \
    u32 A0 = cvtpk(stv[8 * ksl + 0], stv[8 * ksl + 1]);                       \
    u32 A1 = cvtpk(stv[8 * ksl + 2], stv[8 * ksl + 3]);                       \
    u32 B0 = cvtpk(stv[8 * ksl + 4], stv[8 * ksl + 5]);                       \
    u32 B1 = cvtpk(stv[8 * ksl + 6], stv[8 * ksl + 7]);                       \
    asm("v_permlane32_swap_b32 %0, %1" : "+v"(A0), "+v"(B0));                 \
    asm("v_permlane32_swap_b32 %0, %1" : "+v"(A1), "+v"(B1));                 \
    u32x4 pw; pw.x = A0; pw.y = A1; pw.z = B0; pw.w = B1;                     \
    pa = __builtin_bit_cast(bf16x8, pw);                                      \
  }

  // PV of the in-flight tile: pure-register 16-MFMA cluster
#define PVSTEP()                                                              \
  {                                                                           \
    __builtin_amdgcn_s_setprio(1);                                            \
    _Pragma("unroll")                                                         \
    for (int sl = 0; sl < 4; ++sl)                                            \
      _Pragma("unroll")                                                       \
      for (int ds2 = 0; ds2 < 2; ++ds2) {                                     \
        accA[ds2] = __builtin_amdgcn_mfma_f32_32x32x16_bf16(                  \
            paA[sl], vfr[sl * 2 + ds2], accA[ds2], 0, 0, 0);                  \
        accB[ds2] = __builtin_amdgcn_mfma_f32_32x32x16_bf16(                  \
            paB[sl], vfr[sl * 2 + ds2], accB[ds2], 0, 0, 0);                  \
      }                                                                       \
    __builtin_amdgcn_s_setprio(0);                                            \
  }

  // QK(tile in buf CUR) -> exp2 -> pack into pa; vread V into vfr
#define COMPUTE(CUR)                                                          \
  {                                                                           \
    const char* kl = S_lds[kvh][CUR];                                         \
    const char* vl = kl + 8192;                                               \
    f32x16 stA0 = {}, stA1 = {}, stB0 = {}, stB1 = {};                        \
    __builtin_amdgcn_s_setprio(1);                                            \
    _Pragma("unroll")                                                         \
    for (int ds = 0; ds < 4; ++ds) {                                          \
      const int r0 = lo, r1 = 32 + lo;                                        \
      const int col = ds * 32 + hi5 * 16;                                     \
      bf16x8 kf0 = ld8(kl + r0 * 128 + (col ^ ((r0 & 7) << 4)));              \
      bf16x8 kf1 = ld8(kl + r1 * 128 + (col ^ ((r1 & 7) << 4)));              \
      stA0 = __builtin_amdgcn_mfma_f32_32x32x16_bf16(kf0, qfA[ds], stA0,0,0,0);\
      stB0 = __builtin_amdgcn_mfma_f32_32x32x16_bf16(kf0, qfB[ds], stB0,0,0,0);\
      stA1 = __builtin_amdgcn_mfma_f32_32x32x16_bf16(kf1, qfA[ds], stA1,0,0,0);\
      stB1 = __builtin_amdgcn_mfma_f32_32x32x16_bf16(kf1, qfB[ds], stB1,0,0,0);\
    }                                                                         \
    __builtin_amdgcn_s_setprio(0);                                            \
    _Pragma("unroll")                                                         \
    for (int sl = 0; sl < 4; ++sl)                                            \
      _Pragma("unroll")                                                       \
      for (int ds2 = 0; ds2 < 2; ++ds2) {                                     \
        const int row = ds2 * 32 + lo;                                        \
        vfr[sl * 2 + ds2] = ld8(vl + row * 128 +                              \
                                ((sl * 32 + hi5 * 16) ^ ((row & 7) << 4)));   \
      }                                                                       \
    f32x2 ltA; ltA.x = 0.f; ltA.y = 0.f;                                      \
    f32x2 ltB; ltB.x = 0.f; ltB.y = 0.f;                                      \
    _Pragma("unroll")                                                         \
    for (int i = 0; i < 8; ++i) {                                             \
      stA0[2*i]   = __builtin_amdgcn_exp2f(stA0[2*i]);                        \
      stA0[2*i+1] = __builtin_amdgcn_exp2f(stA0[2*i+1]);                      \
      f32x2 a0; a0.x = stA0[2*i]; a0.y = stA0[2*i+1]; ltA += a0;              \
      stA1[2*i]   = __builtin_amdgcn_exp2f(stA1[2*i]);                        \
      stA1[2*i+1] = __builtin_amdgcn_exp2f(stA1[2*i+1]);                      \
      f32x2 a1; a1.x = stA1[2*i]; a1.y = stA1[2*i+1]; ltA += a1;              \
      stB0[2*i]   = __builtin_amdgcn_exp2f(stB0[2*i]);                        \
      stB0[2*i+1] = __builtin_amdgcn_exp2f(stB0[2*i+1]);                      \
      f32x2 b0; b0.x = stB0[2*i]; b0.y = stB0[2*i+1]; ltB += b0;              \
      stB1[2*i]   = __builtin_amdgcn_exp2f(stB1[2*i]);                        \
      stB1[2*i+1] = __builtin_amdgcn_exp2f(stB1[2*i+1]);                      \
      f32x2 b1; b1.x = stB1[2*i]; b1.y = stB1[2*i+1]; ltB += b1;              \
    }                                                                         \
    lrunA += ltA.x + ltA.y;                                                   \
    lrunB += ltB.x + ltB.y;                                                   \
    PACK(stA0, 0, paA[0]); PACK(stA0, 1, paA[1]);                             \
    PACK(stA1, 0, paA[2]); PACK(stA1, 1, paA[3]);                             \
    PACK(stB0, 0, paB[0]); PACK(stB0, 1, paB[1]);                             \
    PACK(stB1, 0, paB[2]); PACK(stB1, 1, paB[3]);                             \
  }

  const int kvbase = kvh * 2048;
  // ---- pipeline prologue: stage 0,1; compute tile 0 (no PV yet)
  STAGE(0, kvbase);
  __syncthreads();                    // tile 0 ready
  STAGE(1, kvbase + 64);
  COMPUTE(0);
  __syncthreads();                    // tile 1 ready; tile 0 reads done

  // ---- steady state: PV(t-1) [regs] || STAGE(t+1) || QK/exp2/pack(t)
  for (int t = 1; t < 32; ++t) {
    const int cur = t & 1;
    if (t < 31) STAGE(cur ^ 1, kvbase + (t + 1) * 64);
    PVSTEP();                         // tile t-1, pure registers
    if (cur) { COMPUTE(1); } else { COMPUTE(0); }
    __syncthreads();                  // tile t+1 landed; tile t reads done
  }
  PVSTEP();                           // tile 31

  // ---- complete per-row l sums across lane halves BEFORE combine
  lrunA += __shfl_xor(lrunA, 32);
  lrunB += __shfl_xor(lrunB, 32);
  // ---- combine the two kv-halves through LDS, then write [S,B,E] bf16
  // Ob overlays staging LDS (safe: loop-final barrier drained all reads)
  float* Ob = (float*)S_lds;          // [(wq*2+qt)*32 + q][64 d] f32 = 32 KB
  if (w >= 2) {                       // kv-half 1 publishes its state
#pragma unroll
    for (int r = 0; r < 16; ++r) {
      const int crow = (r & 3) + 8 * (r >> 2) + 4 * hi5;
#pragma unroll
      for (int ds2 = 0; ds2 < 2; ++ds2) {
        Ob[((wq * 2 + 0) * 32 + crow) * 64 + ds2 * 32 + lo] = accA[ds2][r];
        Ob[((wq * 2 + 1) * 32 + crow) * 64 + ds2 * 32 + lo] = accB[ds2][r];
      }
    }
    if (hi5 == 0) { Ml[wq][0][lo] = lrunA; Ml[wq][1][lo] = lrunB; }
  }
  __syncthreads();
  if (w < 2) {                        // kv-half 0 merges and writes out
    const float linvA = 1.0f / (lrunA + Ml[wq][0][lo]);
    const float linvB = 1.0f / (lrunB + Ml[wq][1][lo]);
    const int b = bh >> 3, h = bh & 7;
#pragma unroll
    for (int r = 0; r < 16; ++r) {
      const int crow = (r & 3) + 8 * (r >> 2) + 4 * hi5;
      const float ivA = __shfl(linvA, crow);
      const float ivB = __shfl(linvB, crow);
      const int sA = q0 + crow, sB = q0 + 32 + crow;
#pragma unroll
      for (int ds2 = 0; ds2 < 2; ++ds2) {
        const float oA = Ob[((wq * 2 + 0) * 32 + crow) * 64 + ds2 * 32 + lo];
        const float oB = Ob[((wq * 2 + 1) * 32 + crow) * 64 + ds2 * 32 + lo];
        attn[(size_t)(sA * 2 + b) * 512 + h * 64 + ds2 * 32 + lo] =
            f2bf((accA[ds2][r] + oA) * ivA);
        attn[(size_t)(sB * 2 + b) * 512 + h * 64 + ds2 * 32 + lo] =
            f2bf((accB[ds2][r] + oB) * ivB);
      }
    }
  }
#undef STAGE
#undef PACK
#undef PVSTEP
#undef COMPUTE
}

// ---------------- launcher ------------------------------------------------
extern "C" void kernel_launch(void* const* d_in, const int* in_sizes, int n_in,
                              void* d_out, int out_size, void* d_ws, size_t ws_size,
                              hipStream_t stream) {
  const float* x     = (const float*)d_in[0];
  const float* w_in  = (const float*)d_in[1];
  const float* b_in  = (const float*)d_in[2];
  const float* w_out = (const float*)d_in[3];
  const float* b_out = (const float*)d_in[4];
  float* out = (float*)d_out;
  char* ws = (char*)d_ws;
  // layout (bytes):
  u16* xb  = (u16*)(ws);               // 8,388,608   x bf16 [8192][512]
  u16* wb  = (u16*)(ws + 8388608);     // 1,572,864   in_proj_w bf16 [1536][512]
  u16* ob  = (u16*)(ws + 9961472);     //   524,288   out_w bf16 [512][512]
  u16* qb  = (u16*)(ws + 10485760);    // 8,388,608   q bf16 [16][4096][64] (pre-scaled)
  u16* kb  = (u16*)(ws + 18874368);    // 8,388,608   k
  u16* vtb = (u16*)(ws + 35651584);    // 8,388,608   v^T [16][64][4096] (written
                                       //             directly by gemm<0> epilogue)
  u16* attn = xb;                      // alias: xb fully consumed by gemm<0>

  cvt_kernel<<<5120, 256, 0, stream>>>(x, w_in, w_out, xb, wb, ob);
  gemm_bt<0, 4><<<dim3(64, 12), 256, 0, stream>>>(xb, wb, b_in, qb, kb, vtb,
                                                  nullptr, 8192, 1536, 512);
  fa_kernel<<<512, 256, 0, stream>>>(qb, kb, vtb, attn);
  gemm_bt<1, 2><<<dim3(64, 8), 256, 0, stream>>>(attn, ob, b_out, nullptr,
                                                 nullptr, nullptr, out,
                                                 8192, 512, 512);
}